// Round 3
// baseline (200.554 us; speedup 1.0000x reference)
//
#include <hip/hip_runtime.h>

#define NG 48
#define NT 6                   // 4 A tiles per axis (8 cells)
#define NTILES (NT * NT * NT)  // 216
#define CAP 1536               // max atoms per (type,tile) list; expected max ~1040

// ws layout: [0, 2592)            int cnt[3*216]
//            [4096, 4096+2MB)     uint16 lists[3*216][CAP]
#define LISTS_OFF 4096

__device__ __forceinline__ float type_r(int type) {
    return (type == 0) ? 1.7f : ((type == 1) ? 1.55f : 1.52f);
}

// Phase 1: bin each (atom,type) into every 4A tile whose cell-center range
// [4t, 4t+3.5] intersects the atom's 1.5r halo. Atom indices are uint16.
__global__ __launch_bounds__(256) void bin_kernel(
    const float* __restrict__ vC,
    const float* __restrict__ vN,
    const float* __restrict__ vO,
    int* __restrict__ cnt,
    unsigned short* __restrict__ lists,
    int natoms)
{
    const int type = blockIdx.y;
    const float r = type_r(type);
    const float b = 1.5f * r + 1e-3f;   // tiny pad: boundary cells contribute ~0 anyway
    const float* __restrict__ vecs = (type == 0) ? vC : ((type == 1) ? vN : vO);

    const int i = blockIdx.x * 256 + threadIdx.x;
    if (i >= natoms) return;

    const float vx = vecs[3 * i + 0] + 23.5f;  // vec = raw + 48*0.5 - 0.5
    const float vy = vecs[3 * i + 1] + 23.5f;
    const float vz = vecs[3 * i + 2] + 23.5f;

    // tile t intersects halo iff 4t > v - b - 3.5 and 4t < v + b
    int x0 = max(0,      (int)floorf((vx - 3.5f - b) * 0.25f) + 1);
    int x1 = min(NT - 1, (int)ceilf ((vx + b)        * 0.25f) - 1);
    int y0 = max(0,      (int)floorf((vy - 3.5f - b) * 0.25f) + 1);
    int y1 = min(NT - 1, (int)ceilf ((vy + b)        * 0.25f) - 1);
    int z0 = max(0,      (int)floorf((vz - 3.5f - b) * 0.25f) + 1);
    int z1 = min(NT - 1, (int)ceilf ((vz + b)        * 0.25f) - 1);
    if (x0 > x1 || y0 > y1 || z0 > z1) return;

    const int tbase = type * NTILES;
    for (int tx = x0; tx <= x1; ++tx)
        for (int ty = y0; ty <= y1; ++ty)
            for (int tz = z0; tz <= z1; ++tz) {
                const int t = tbase + (tx * NT + ty) * NT + tz;
                const int pos = atomicAdd(&cnt[t], 1);
                if (pos < CAP)
                    lists[(size_t)t * CAP + pos] = (unsigned short)i;
            }
}

// Phase 2: one block per (tile,type). 256 threads, 2 cells each (x and x+4).
// Stage list atoms into LDS in 256-chunks (float4 -> one ds_read_b128
// broadcast per eval iteration), accumulate in registers, store once.
__global__ __launch_bounds__(256) void gather_kernel(
    const float* __restrict__ vC,
    const float* __restrict__ vN,
    const float* __restrict__ vO,
    const int* __restrict__ cnt,
    const unsigned short* __restrict__ lists,
    float* __restrict__ out)
{
    const int type = blockIdx.y;
    const float r = type_r(type);
    const float* __restrict__ vecs = (type == 0) ? vC : ((type == 1) ? vN : vO);

    const int t  = blockIdx.x;
    const int tx = t / (NT * NT);
    const int ty = (t / NT) % NT;
    const int tz = t % NT;

    const int tid = threadIdx.x;
    const int lx  = tid >> 6;
    const int ly  = (tid >> 3) & 7;
    const int lz  = tid & 7;

    const float b      = 1.5f * r;
    const float r15sq  = b * b;
    const float rr     = r * r;
    const float E2     = 7.3890562f;
    const float c2a    = 4.0f / (E2 * rr);
    const float c2b    = 12.0f / (E2 * r);
    const float c2c    = 9.0f / E2;
    const float n2orr  = -2.0f / rr;

    const float px0 = 0.5f * (float)(tx * 8 + lx);
    const float px1 = px0 + 2.0f;
    const float py  = 0.5f * (float)(ty * 8 + ly);
    const float pz  = 0.5f * (float)(tz * 8 + lz);

    __shared__ float4 sa[256];

    const int lt = type * NTILES + t;
    const int n  = min(cnt[lt], CAP);
    const unsigned short* __restrict__ lst = lists + (size_t)lt * CAP;

    float acc0 = 0.0f, acc1 = 0.0f;

    for (int base = 0; base < n; base += 256) {
        const int m = min(256, n - base);
        __syncthreads();
        if (tid < m) {
            const int idx = (int)lst[base + tid];
            sa[tid] = make_float4(vecs[3 * idx + 0] + 23.5f,
                                  vecs[3 * idx + 1] + 23.5f,
                                  vecs[3 * idx + 2] + 23.5f, 0.0f);
        }
        __syncthreads();

        for (int j = 0; j < m; ++j) {
            const float4 a = sa[j];               // one b128 broadcast
            const float dy  = a.y - py;
            const float dz  = a.z - pz;
            const float syz = fmaf(dy, dy, dz * dz);
            const float dx0 = a.x - px0;
            const float d2a = fmaf(dx0, dx0, syz);
            const float dx1 = a.x - px1;
            const float d2b = fmaf(dx1, dx1, syz);
            if (d2a < r15sq) {
                const float d = sqrtf(d2a);
                acc0 += (d < r) ? __expf(n2orr * d2a)
                                : fmaf(c2a, d2a, fmaf(-c2b, d, c2c));
            }
            if (d2b < r15sq) {
                const float d = sqrtf(d2b);
                acc1 += (d < r) ? __expf(n2orr * d2b)
                                : fmaf(c2a, d2b, fmaf(-c2b, d, c2c));
            }
        }
    }

    const int X0 = tx * 8 + lx;
    const int Y  = ty * 8 + ly;
    const int Z  = tz * 8 + lz;
    float* __restrict__ o = out + (size_t)type * NG * NG * NG;
    o[((X0      * NG) + Y) * NG + Z] = acc0;
    o[(((X0 + 4) * NG) + Y) * NG + Z] = acc1;
}

extern "C" void kernel_launch(void* const* d_in, const int* in_sizes, int n_in,
                              void* d_out, int out_size, void* d_ws, size_t ws_size,
                              hipStream_t stream) {
    const float* vC = (const float*)d_in[0];
    const float* vN = (const float*)d_in[1];
    const float* vO = (const float*)d_in[2];
    float* out = (float*)d_out;

    int* cnt = (int*)d_ws;
    unsigned short* lists = (unsigned short*)((char*)d_ws + LISTS_OFF);

    const int natoms = in_sizes[0] / 3;   // 16384

    hipMemsetAsync(cnt, 0, 3 * NTILES * sizeof(int), stream);

    dim3 bgrid((natoms + 255) / 256, 3, 1);
    bin_kernel<<<bgrid, 256, 0, stream>>>(vC, vN, vO, cnt, lists, natoms);

    dim3 ggrid(NTILES, 3, 1);
    gather_kernel<<<ggrid, 256, 0, stream>>>(vC, vN, vO, cnt, lists, out);
}

// Round 4
// 157.763 us; speedup vs baseline: 1.2712x; 1.2712x over previous
//
#include <hip/hip_runtime.h>

#define NG 48
#define NT 6                   // 4 A tiles per axis (8 cells)
#define NTILES (NT * NT * NT)  // 216
#define CAP 1536               // max atoms per (type,tile); expected max ~1010
#define LISTS_OFF 4096
#define NPLANE (NTILES * 8)    // 1728 (tile, x-plane) blocks per type

__device__ __forceinline__ float type_r(int type) {
    return (type == 0) ? 1.7f : ((type == 1) ? 1.55f : 1.52f);
}

// Phase 1: bin each (atom,type) into every 4A tile whose cell-center range
// [4t, 4t+3.5] intersects the atom's 1.5r halo (superset of true support).
__global__ __launch_bounds__(256) void bin_kernel(
    const float* __restrict__ vC,
    const float* __restrict__ vN,
    const float* __restrict__ vO,
    int* __restrict__ cnt,
    unsigned short* __restrict__ lists,
    int natoms)
{
    const int type = blockIdx.y;
    const float r = type_r(type);
    const float b = 1.5f * r + 1e-3f;
    const float* __restrict__ vecs = (type == 0) ? vC : ((type == 1) ? vN : vO);

    const int i = blockIdx.x * 256 + threadIdx.x;
    if (i >= natoms) return;

    const float vx = vecs[3 * i + 0] + 23.5f;  // vec = raw + 48*0.5 - 0.5
    const float vy = vecs[3 * i + 1] + 23.5f;
    const float vz = vecs[3 * i + 2] + 23.5f;

    int x0 = max(0,      (int)floorf((vx - 3.5f - b) * 0.25f) + 1);
    int x1 = min(NT - 1, (int)ceilf ((vx + b)        * 0.25f) - 1);
    int y0 = max(0,      (int)floorf((vy - 3.5f - b) * 0.25f) + 1);
    int y1 = min(NT - 1, (int)ceilf ((vy + b)        * 0.25f) - 1);
    int z0 = max(0,      (int)floorf((vz - 3.5f - b) * 0.25f) + 1);
    int z1 = min(NT - 1, (int)ceilf ((vz + b)        * 0.25f) - 1);
    if (x0 > x1 || y0 > y1 || z0 > z1) return;

    const int tbase = type * NTILES;
    for (int tx = x0; tx <= x1; ++tx)
        for (int ty = y0; ty <= y1; ++ty)
            for (int tz = z0; tz <= z1; ++tz) {
                const int t = tbase + (tx * NT + ty) * NT + tz;
                const int pos = atomicAdd(&cnt[t], 1);
                if (pos < CAP)
                    lists[(size_t)t * CAP + pos] = (unsigned short)i;
            }
}

// Phase 2: one SINGLE-WAVE block per (tile, x-plane, type). Lane owns cell
// (y,z) of the plane. Stage 64 atoms/chunk into LDS, evaluate with a uniform
// x-cull and a whole-wave hit-cull. Each output cell stored exactly once.
__global__ __launch_bounds__(64) void gather_kernel(
    const float* __restrict__ vC,
    const float* __restrict__ vN,
    const float* __restrict__ vO,
    const int* __restrict__ cnt,
    const unsigned short* __restrict__ lists,
    float* __restrict__ out)
{
    const int type = blockIdx.y;
    const float r = type_r(type);
    const float* __restrict__ vecs = (type == 0) ? vC : ((type == 1) ? vN : vO);

    // coprime permutation spreads heavy (clustered) tiles across CUs
    const int pb = (int)((blockIdx.x * 997u) % (unsigned)NPLANE);
    const int t  = pb >> 3;
    const int xp = pb & 7;
    const int tx = t / (NT * NT);
    const int ty = (t / NT) % NT;
    const int tz = t % NT;

    const int tid = threadIdx.x;   // 0..63
    const int ly  = tid >> 3;
    const int lz  = tid & 7;

    const float b      = 1.5f * r;
    const float r15sq  = b * b;
    const float rr     = r * r;
    const float E2     = 7.3890562f;
    const float c2a    = 4.0f / (E2 * rr);
    const float c2b    = 12.0f / (E2 * r);
    const float c2c    = 9.0f / E2;
    const float n2orr  = -2.0f / rr;

    const float px = 0.5f * (float)(tx * 8 + xp);
    const float py = 0.5f * (float)(ty * 8 + ly);
    const float pz = 0.5f * (float)(tz * 8 + lz);

    __shared__ float4 sa[64];

    const int lt = type * NTILES + t;
    const int n  = min(cnt[lt], CAP);
    const unsigned short* __restrict__ lst = lists + (size_t)lt * CAP;

    float acc = 0.0f;

    for (int base = 0; base < n; base += 64) {
        const int m = min(64, n - base);
        if (tid < m) {
            const int idx = (int)lst[base + tid];
            sa[tid] = make_float4(vecs[3 * idx + 0] + 23.5f,
                                  vecs[3 * idx + 1] + 23.5f,
                                  vecs[3 * idx + 2] + 23.5f, 0.0f);
        }
        __syncthreads();

        for (int j = 0; j < m; ++j) {
            const float4 a = sa[j];          // broadcast
            const float dx  = a.x - px;      // uniform across wave
            const float dxx = dx * dx;
            if (dxx >= r15sq) continue;      // uniform branch: plane cull
            const float dy = a.y - py;
            const float dz = a.z - pz;
            const float d2 = fmaf(dy, dy, fmaf(dz, dz, dxx));
            const bool hit = d2 < r15sq;
            if (__ballot(hit) == 0ull) continue;  // whole-wave miss cull
            const float d  = sqrtf(d2);
            const float f1 = __expf(n2orr * d2);
            const float f2 = fmaf(c2a, d2, fmaf(-c2b, d, c2c));
            const float v  = (d < r) ? f1 : f2;
            acc += hit ? v : 0.0f;
        }
        __syncthreads();
    }

    const int X = tx * 8 + xp;
    const int Y = ty * 8 + ly;
    const int Z = tz * 8 + lz;
    out[((size_t)type * NG * NG * NG) + ((size_t)X * NG + Y) * NG + Z] = acc;
}

extern "C" void kernel_launch(void* const* d_in, const int* in_sizes, int n_in,
                              void* d_out, int out_size, void* d_ws, size_t ws_size,
                              hipStream_t stream) {
    const float* vC = (const float*)d_in[0];
    const float* vN = (const float*)d_in[1];
    const float* vO = (const float*)d_in[2];
    float* out = (float*)d_out;

    int* cnt = (int*)d_ws;
    unsigned short* lists = (unsigned short*)((char*)d_ws + LISTS_OFF);

    const int natoms = in_sizes[0] / 3;   // 16384

    hipMemsetAsync(cnt, 0, 3 * NTILES * sizeof(int), stream);

    dim3 bgrid((natoms + 255) / 256, 3, 1);
    bin_kernel<<<bgrid, 256, 0, stream>>>(vC, vN, vO, cnt, lists, natoms);

    dim3 ggrid(NPLANE, 3, 1);
    gather_kernel<<<ggrid, 64, 0, stream>>>(vC, vN, vO, cnt, lists, out);
}

// Round 5
// 90.630 us; speedup vs baseline: 2.2129x; 1.7407x over previous
//
#include <hip/hip_runtime.h>

#define NG 48
#define NT 6                   // 4 A tiles per axis (8 cells)
#define NTILES (NT * NT * NT)  // 216
#define CAP 1536               // max atoms per (type,tile); expected max ~1010
#define LISTS_OFF 4096
#define COPIES_OFF (2u << 20)            // 2 MiB (lists end at ~1.99 MB)
#define GRID_FLOATS (3 * NG * NG * NG)   // 331776 floats per partial copy
#define MAXSEG 8

__device__ __forceinline__ float type_r(int type) {
    return (type == 0) ? 1.7f : ((type == 1) ? 1.55f : 1.52f);
}

// Phase 1: bin each (atom,type) into every 4A tile whose cell-center range
// [4t, 4t+3.5] intersects the atom's 1.5r halo (superset of true support,
// so the gather predicate d < 1.5r is exact).
__global__ __launch_bounds__(256) void bin_kernel(
    const float* __restrict__ vC,
    const float* __restrict__ vN,
    const float* __restrict__ vO,
    int* __restrict__ cnt,
    unsigned short* __restrict__ lists,
    int natoms)
{
    const int type = blockIdx.y;
    const float r = type_r(type);
    const float b = 1.5f * r + 1e-3f;
    const float* __restrict__ vecs = (type == 0) ? vC : ((type == 1) ? vN : vO);

    const int i = blockIdx.x * 256 + threadIdx.x;
    if (i >= natoms) return;

    const float vx = vecs[3 * i + 0] + 23.5f;  // vec = raw + 48*0.5 - 0.5
    const float vy = vecs[3 * i + 1] + 23.5f;
    const float vz = vecs[3 * i + 2] + 23.5f;

    int x0 = max(0,      (int)floorf((vx - 3.5f - b) * 0.25f) + 1);
    int x1 = min(NT - 1, (int)ceilf ((vx + b)        * 0.25f) - 1);
    int y0 = max(0,      (int)floorf((vy - 3.5f - b) * 0.25f) + 1);
    int y1 = min(NT - 1, (int)ceilf ((vy + b)        * 0.25f) - 1);
    int z0 = max(0,      (int)floorf((vz - 3.5f - b) * 0.25f) + 1);
    int z1 = min(NT - 1, (int)ceilf ((vz + b)        * 0.25f) - 1);
    if (x0 > x1 || y0 > y1 || z0 > z1) return;

    const int tbase = type * NTILES;
    for (int tx = x0; tx <= x1; ++tx)
        for (int ty = y0; ty <= y1; ++ty)
            for (int tz = z0; tz <= z1; ++tz) {
                const int t = tbase + (tx * NT + ty) * NT + tz;
                const int pos = atomicAdd(&cnt[t], 1);
                if (pos < CAP)
                    lists[(size_t)t * CAP + pos] = (unsigned short)i;
            }
}

// Phase 2: one 256-thread block per (tile, type, list-segment). Thread owns
// cells (x,y,z) and (x+4,y,z). Block evaluates only its segment of the list
// and plain-stores 512 partial sums into partial grid copy `s` (no atomics).
// Every block writes all its cells, so copies need no zero-fill.
__global__ __launch_bounds__(256) void gather_seg(
    const float* __restrict__ vC,
    const float* __restrict__ vN,
    const float* __restrict__ vO,
    const int* __restrict__ cnt,
    const unsigned short* __restrict__ lists,
    float* __restrict__ copies,
    int nseg)
{
    const int type = blockIdx.y;
    const float r = type_r(type);
    const float* __restrict__ vecs = (type == 0) ? vC : ((type == 1) ? vN : vO);

    const int t = blockIdx.x / nseg;
    const int s = blockIdx.x - t * nseg;
    const int tx = t / (NT * NT);
    const int ty = (t / NT) % NT;
    const int tz = t % NT;

    const int tid = threadIdx.x;
    const int lx  = tid >> 6;          // 0..3
    const int ly  = (tid >> 3) & 7;
    const int lz  = tid & 7;

    const float b      = 1.5f * r;
    const float r15sq  = b * b;
    const float rr     = r * r;
    const float E2     = 7.3890562f;
    const float c2a    = 4.0f / (E2 * rr);
    const float c2b    = 12.0f / (E2 * r);
    const float c2c    = 9.0f / E2;
    const float n2orr  = -2.0f / rr;

    const float px0 = 0.5f * (float)(tx * 8 + lx);
    const float px1 = px0 + 2.0f;
    const float py  = 0.5f * (float)(ty * 8 + ly);
    const float pz  = 0.5f * (float)(tz * 8 + lz);

    __shared__ float4 sa[256];

    const int lt = type * NTILES + t;
    const int n  = min(cnt[lt], CAP);
    const int len   = (n + nseg - 1) / nseg;
    const int start = s * len;
    const int end   = min(n, start + len);
    const unsigned short* __restrict__ lst = lists + (size_t)lt * CAP;

    float acc0 = 0.0f, acc1 = 0.0f;

    for (int base = start; base < end; base += 256) {
        const int m = min(256, end - base);
        if (tid < m) {
            const int idx = (int)lst[base + tid];
            sa[tid] = make_float4(vecs[3 * idx + 0] + 23.5f,
                                  vecs[3 * idx + 1] + 23.5f,
                                  vecs[3 * idx + 2] + 23.5f, 0.0f);
        }
        __syncthreads();

        for (int j = 0; j < m; ++j) {
            const float4 a = sa[j];               // one b128 LDS broadcast
            const float dy  = a.y - py;
            const float dz  = a.z - pz;
            const float syz = fmaf(dy, dy, dz * dz);
            const float dx0 = a.x - px0;
            const float d2a = fmaf(dx0, dx0, syz);
            const float dx1 = a.x - px1;
            const float d2b = fmaf(dx1, dx1, syz);
            const bool h0 = d2a < r15sq;
            const bool h1 = d2b < r15sq;
            if (__ballot(h0 | h1) == 0ull) continue;   // whole-wave miss cull
            if (h0) {
                const float d = sqrtf(d2a);
                acc0 += (d < r) ? __expf(n2orr * d2a)
                                : fmaf(c2a, d2a, fmaf(-c2b, d, c2c));
            }
            if (h1) {
                const float d = sqrtf(d2b);
                acc1 += (d < r) ? __expf(n2orr * d2b)
                                : fmaf(c2a, d2b, fmaf(-c2b, d, c2c));
            }
        }
        __syncthreads();
    }

    const int X0 = tx * 8 + lx;
    const int Y  = ty * 8 + ly;
    const int Z  = tz * 8 + lz;
    float* __restrict__ o = copies + (size_t)s * GRID_FLOATS
                                   + (size_t)type * NG * NG * NG;
    o[((X0      * NG) + Y) * NG + Z] = acc0;
    o[(((X0 + 4) * NG) + Y) * NG + Z] = acc1;
}

// Phase 3: out[i] = sum over segments of copies[s][i]. float4, plain stores.
__global__ __launch_bounds__(256) void reduce_kernel(
    const float* __restrict__ copies,
    float* __restrict__ out,
    int nseg)
{
    const int i4 = blockIdx.x * 256 + threadIdx.x;   // float4 index
    if (i4 >= GRID_FLOATS / 4) return;
    const float4* __restrict__ c = (const float4*)copies;
    float4 acc = c[i4];
    for (int s = 1; s < nseg; ++s) {
        const float4 v = c[(size_t)s * (GRID_FLOATS / 4) + i4];
        acc.x += v.x; acc.y += v.y; acc.z += v.z; acc.w += v.w;
    }
    ((float4*)out)[i4] = acc;
}

extern "C" void kernel_launch(void* const* d_in, const int* in_sizes, int n_in,
                              void* d_out, int out_size, void* d_ws, size_t ws_size,
                              hipStream_t stream) {
    const float* vC = (const float*)d_in[0];
    const float* vN = (const float*)d_in[1];
    const float* vO = (const float*)d_in[2];
    float* out = (float*)d_out;

    int* cnt = (int*)d_ws;
    unsigned short* lists = (unsigned short*)((char*)d_ws + LISTS_OFF);
    float* copies = (float*)((char*)d_ws + COPIES_OFF);

    // clamp segment count to what the workspace can hold
    const size_t copy_bytes = (size_t)GRID_FLOATS * sizeof(float);
    long avail = (long)((ws_size - COPIES_OFF) / copy_bytes);
    int nseg = (int)(avail < 1 ? 1 : (avail > MAXSEG ? MAXSEG : avail));
    if (nseg > 6) nseg = 6;

    const int natoms = in_sizes[0] / 3;   // 16384

    hipMemsetAsync(cnt, 0, 3 * NTILES * sizeof(int), stream);

    dim3 bgrid((natoms + 255) / 256, 3, 1);
    bin_kernel<<<bgrid, 256, 0, stream>>>(vC, vN, vO, cnt, lists, natoms);

    dim3 ggrid(NTILES * nseg, 3, 1);
    gather_seg<<<ggrid, 256, 0, stream>>>(vC, vN, vO, cnt, lists, copies, nseg);

    dim3 rgrid((GRID_FLOATS / 4 + 255) / 256, 1, 1);
    reduce_kernel<<<rgrid, 256, 0, stream>>>(copies, out, nseg);
}

// Round 6
// 88.073 us; speedup vs baseline: 2.2771x; 1.0290x over previous
//
#include <hip/hip_runtime.h>

#define NG 48
#define NT 6                   // 4 A tiles per axis (8 cells)
#define NTILES (NT * NT * NT)  // 216
#define CAP 1536               // max atoms per (type,tile); expected max ~1010
#define LISTS_OFF 4096
#define COPIES_OFF (2u << 20)            // 2 MiB (lists end at ~1.99 MB)
#define GRID_FLOATS (3 * NG * NG * NG)   // 331776 floats per partial copy
#define MAXSEG 8

__device__ __forceinline__ float type_r(int type) {
    return (type == 0) ? 1.7f : ((type == 1) ? 1.55f : 1.52f);
}

// Phase 1: one thread per (atom, candidate-tile-offset). The 1.5r halo spans
// at most 3 tiles per axis -> 27 offsets. Each thread does at most ONE
// independent atomicAdd (no serial dependent chain), and ~20k waves hide the
// round-trip latency. Adjacent threads share an atom -> vecs loads broadcast.
__global__ __launch_bounds__(256) void bin_kernel(
    const float* __restrict__ vC,
    const float* __restrict__ vN,
    const float* __restrict__ vO,
    int* __restrict__ cnt,
    unsigned short* __restrict__ lists,
    int natoms)
{
    const int gid  = blockIdx.x * 256 + threadIdx.x;
    const int atom = gid / 27;
    const int o    = gid - atom * 27;
    if (atom >= natoms) return;

    const int type = blockIdx.y;
    const float r = type_r(type);
    const float b = 1.5f * r + 1e-3f;
    const float* __restrict__ vecs = (type == 0) ? vC : ((type == 1) ? vN : vO);

    const float vx = vecs[3 * atom + 0] + 23.5f;  // vec = raw + 48*0.5 - 0.5
    const float vy = vecs[3 * atom + 1] + 23.5f;
    const float vz = vecs[3 * atom + 2] + 23.5f;

    // tile t intersects halo iff 4t > v - b - 3.5 and 4t < v + b
    const int x0 = max(0,      (int)floorf((vx - 3.5f - b) * 0.25f) + 1);
    const int x1 = min(NT - 1, (int)ceilf ((vx + b)        * 0.25f) - 1);
    const int y0 = max(0,      (int)floorf((vy - 3.5f - b) * 0.25f) + 1);
    const int y1 = min(NT - 1, (int)ceilf ((vy + b)        * 0.25f) - 1);
    const int z0 = max(0,      (int)floorf((vz - 3.5f - b) * 0.25f) + 1);
    const int z1 = min(NT - 1, (int)ceilf ((vz + b)        * 0.25f) - 1);

    const int tx = x0 + o / 9;
    const int ty = y0 + (o / 3) % 3;
    const int tz = z0 + o % 3;
    if (tx > x1 || ty > y1 || tz > z1) return;

    const int t = type * NTILES + (tx * NT + ty) * NT + tz;
    const int pos = atomicAdd(&cnt[t], 1);
    if (pos < CAP)
        lists[(size_t)t * CAP + pos] = (unsigned short)atom;
}

// Phase 2: one 256-thread block per (tile, type, list-segment). Thread owns
// cells (x,y,z) and (x+4,y,z). Block evaluates only its segment of the list
// and plain-stores 512 partial sums into partial grid copy `s` (no atomics).
// Every block writes all its cells, so copies need no zero-fill.
__global__ __launch_bounds__(256) void gather_seg(
    const float* __restrict__ vC,
    const float* __restrict__ vN,
    const float* __restrict__ vO,
    const int* __restrict__ cnt,
    const unsigned short* __restrict__ lists,
    float* __restrict__ copies,
    int nseg)
{
    const int type = blockIdx.y;
    const float r = type_r(type);
    const float* __restrict__ vecs = (type == 0) ? vC : ((type == 1) ? vN : vO);

    const int t = blockIdx.x / nseg;
    const int s = blockIdx.x - t * nseg;
    const int tx = t / (NT * NT);
    const int ty = (t / NT) % NT;
    const int tz = t % NT;

    const int tid = threadIdx.x;
    const int lx  = tid >> 6;          // 0..3
    const int ly  = (tid >> 3) & 7;
    const int lz  = tid & 7;

    const float b      = 1.5f * r;
    const float r15sq  = b * b;
    const float rr     = r * r;
    const float E2     = 7.3890562f;
    const float c2a    = 4.0f / (E2 * rr);
    const float c2b    = 12.0f / (E2 * r);
    const float c2c    = 9.0f / E2;
    const float n2orr  = -2.0f / rr;

    const float px0 = 0.5f * (float)(tx * 8 + lx);
    const float px1 = px0 + 2.0f;
    const float py  = 0.5f * (float)(ty * 8 + ly);
    const float pz  = 0.5f * (float)(tz * 8 + lz);

    __shared__ float4 sa[256];

    const int lt = type * NTILES + t;
    const int n  = min(cnt[lt], CAP);
    const int len   = (n + nseg - 1) / nseg;
    const int start = s * len;
    const int end   = min(n, start + len);
    const unsigned short* __restrict__ lst = lists + (size_t)lt * CAP;

    float acc0 = 0.0f, acc1 = 0.0f;

    for (int base = start; base < end; base += 256) {
        const int m = min(256, end - base);
        if (tid < m) {
            const int idx = (int)lst[base + tid];
            sa[tid] = make_float4(vecs[3 * idx + 0] + 23.5f,
                                  vecs[3 * idx + 1] + 23.5f,
                                  vecs[3 * idx + 2] + 23.5f, 0.0f);
        }
        __syncthreads();

        for (int j = 0; j < m; ++j) {
            const float4 a = sa[j];               // one b128 LDS broadcast
            const float dy  = a.y - py;
            const float dz  = a.z - pz;
            const float syz = fmaf(dy, dy, dz * dz);
            const float dx0 = a.x - px0;
            const float d2a = fmaf(dx0, dx0, syz);
            const float dx1 = a.x - px1;
            const float d2b = fmaf(dx1, dx1, syz);
            const bool h0 = d2a < r15sq;
            const bool h1 = d2b < r15sq;
            if (__ballot(h0 | h1) == 0ull) continue;   // whole-wave miss cull
            if (h0) {
                const float d = sqrtf(d2a);
                acc0 += (d < r) ? __expf(n2orr * d2a)
                                : fmaf(c2a, d2a, fmaf(-c2b, d, c2c));
            }
            if (h1) {
                const float d = sqrtf(d2b);
                acc1 += (d < r) ? __expf(n2orr * d2b)
                                : fmaf(c2a, d2b, fmaf(-c2b, d, c2c));
            }
        }
        __syncthreads();
    }

    const int X0 = tx * 8 + lx;
    const int Y  = ty * 8 + ly;
    const int Z  = tz * 8 + lz;
    float* __restrict__ o = copies + (size_t)s * GRID_FLOATS
                                   + (size_t)type * NG * NG * NG;
    o[((X0      * NG) + Y) * NG + Z] = acc0;
    o[(((X0 + 4) * NG) + Y) * NG + Z] = acc1;
}

// Phase 3: out[i] = sum over segments of copies[s][i]. float4, plain stores.
__global__ __launch_bounds__(256) void reduce_kernel(
    const float* __restrict__ copies,
    float* __restrict__ out,
    int nseg)
{
    const int i4 = blockIdx.x * 256 + threadIdx.x;   // float4 index
    if (i4 >= GRID_FLOATS / 4) return;
    const float4* __restrict__ c = (const float4*)copies;
    float4 acc = c[i4];
    for (int s = 1; s < nseg; ++s) {
        const float4 v = c[(size_t)s * (GRID_FLOATS / 4) + i4];
        acc.x += v.x; acc.y += v.y; acc.z += v.z; acc.w += v.w;
    }
    ((float4*)out)[i4] = acc;
}

extern "C" void kernel_launch(void* const* d_in, const int* in_sizes, int n_in,
                              void* d_out, int out_size, void* d_ws, size_t ws_size,
                              hipStream_t stream) {
    const float* vC = (const float*)d_in[0];
    const float* vN = (const float*)d_in[1];
    const float* vO = (const float*)d_in[2];
    float* out = (float*)d_out;

    int* cnt = (int*)d_ws;
    unsigned short* lists = (unsigned short*)((char*)d_ws + LISTS_OFF);
    float* copies = (float*)((char*)d_ws + COPIES_OFF);

    // clamp segment count to what the workspace can hold
    const size_t copy_bytes = (size_t)GRID_FLOATS * sizeof(float);
    long avail = (long)((ws_size - COPIES_OFF) / copy_bytes);
    int nseg = (int)(avail < 1 ? 1 : (avail > MAXSEG ? MAXSEG : avail));
    if (nseg > 6) nseg = 6;

    const int natoms = in_sizes[0] / 3;   // 16384

    hipMemsetAsync(cnt, 0, 3 * NTILES * sizeof(int), stream);

    const int npairs = natoms * 27;
    dim3 bgrid((npairs + 255) / 256, 3, 1);
    bin_kernel<<<bgrid, 256, 0, stream>>>(vC, vN, vO, cnt, lists, natoms);

    dim3 ggrid(NTILES * nseg, 3, 1);
    gather_seg<<<ggrid, 256, 0, stream>>>(vC, vN, vO, cnt, lists, copies, nseg);

    dim3 rgrid((GRID_FLOATS / 4 + 255) / 256, 1, 1);
    reduce_kernel<<<rgrid, 256, 0, stream>>>(copies, out, nseg);
}

// Round 7
// 47.111 us; speedup vs baseline: 4.2571x; 1.8695x over previous
//
#include <hip/hip_runtime.h>

#define NG 48
#define NT 6                   // 4 A tiles per axis (8 cells)
#define NTILES (NT * NT * NT)  // 216
#define CAP 1536               // max atoms per (type,tile); expected max ~1010
#define LISTS_OFF 4096
#define COPIES_OFF (2u << 20)            // 2 MiB (lists end at ~1.99 MB)
#define GRID_FLOATS (3 * NG * NG * NG)   // 331776 floats per partial copy
#define MAXSEG 8

__device__ __forceinline__ float type_r(int type) {
    return (type == 0) ? 1.7f : ((type == 1) ? 1.55f : 1.52f);
}

// Phase 1 (two-level histogram): each 256-atom block counts its insertions
// per tile in LDS, reserves a contiguous range in the global list with ONE
// atomicAdd per (block, active tile), then plain-stores entries into the
// reserved range (slot from an LDS fill counter). Global atomic count drops
// from ~130k contended RMWs to ~24k (<=64 per counter), and no global atomic
// sits on a per-entry dependent chain.
__global__ __launch_bounds__(256) void bin_kernel(
    const float* __restrict__ vC,
    const float* __restrict__ vN,
    const float* __restrict__ vO,
    int* __restrict__ cnt,
    unsigned short* __restrict__ lists,
    int natoms)
{
    const int type = blockIdx.y;
    const float r = type_r(type);
    const float b = 1.5f * r + 1e-3f;
    const float* __restrict__ vecs = (type == 0) ? vC : ((type == 1) ? vN : vO);

    const int tid  = threadIdx.x;
    const int atom = blockIdx.x * 256 + tid;

    __shared__ int lcnt[NTILES];
    __shared__ int lbase[NTILES];
    __shared__ int lfill[NTILES];

    if (tid < NTILES) { lcnt[tid] = 0; lfill[tid] = 0; }
    __syncthreads();

    int x0 = 1, x1 = 0, y0 = 1, y1 = 0, z0 = 1, z1 = 0;
    if (atom < natoms) {
        const float vx = vecs[3 * atom + 0] + 23.5f;  // vec = raw + 24 - 0.5
        const float vy = vecs[3 * atom + 1] + 23.5f;
        const float vz = vecs[3 * atom + 2] + 23.5f;
        // tile t intersects halo iff 4t > v - b - 3.5 and 4t < v + b
        x0 = max(0,      (int)floorf((vx - 3.5f - b) * 0.25f) + 1);
        x1 = min(NT - 1, (int)ceilf ((vx + b)        * 0.25f) - 1);
        y0 = max(0,      (int)floorf((vy - 3.5f - b) * 0.25f) + 1);
        y1 = min(NT - 1, (int)ceilf ((vy + b)        * 0.25f) - 1);
        z0 = max(0,      (int)floorf((vz - 3.5f - b) * 0.25f) + 1);
        z1 = min(NT - 1, (int)ceilf ((vz + b)        * 0.25f) - 1);
    }
    const bool has = (x0 <= x1) & (y0 <= y1) & (z0 <= z1);

    if (has)
        for (int tx = x0; tx <= x1; ++tx)
            for (int ty = y0; ty <= y1; ++ty)
                for (int tz = z0; tz <= z1; ++tz)
                    atomicAdd(&lcnt[(tx * NT + ty) * NT + tz], 1);  // LDS
    __syncthreads();

    if (tid < NTILES) {
        const int c = lcnt[tid];
        if (c > 0)
            lbase[tid] = atomicAdd(&cnt[type * NTILES + tid], c);  // global, 1/block/tile
    }
    __syncthreads();

    if (has)
        for (int tx = x0; tx <= x1; ++tx)
            for (int ty = y0; ty <= y1; ++ty)
                for (int tz = z0; tz <= z1; ++tz) {
                    const int tl = (tx * NT + ty) * NT + tz;
                    const int p  = lbase[tl] + atomicAdd(&lfill[tl], 1);  // LDS
                    if (p < CAP)
                        lists[(size_t)(type * NTILES + tl) * CAP + p] =
                            (unsigned short)atom;
                }
}

// Phase 2: one 256-thread block per (tile, type, list-segment). Thread owns
// cells (x,y,z) and (x+4,y,z). Block evaluates only its segment of the list
// and plain-stores 512 partial sums into partial grid copy `s` (no atomics).
// Every block writes all its cells, so copies need no zero-fill.
__global__ __launch_bounds__(256) void gather_seg(
    const float* __restrict__ vC,
    const float* __restrict__ vN,
    const float* __restrict__ vO,
    const int* __restrict__ cnt,
    const unsigned short* __restrict__ lists,
    float* __restrict__ copies,
    int nseg)
{
    const int type = blockIdx.y;
    const float r = type_r(type);
    const float* __restrict__ vecs = (type == 0) ? vC : ((type == 1) ? vN : vO);

    const int t = blockIdx.x / nseg;
    const int s = blockIdx.x - t * nseg;
    const int tx = t / (NT * NT);
    const int ty = (t / NT) % NT;
    const int tz = t % NT;

    const int tid = threadIdx.x;
    const int lx  = tid >> 6;          // 0..3
    const int ly  = (tid >> 3) & 7;
    const int lz  = tid & 7;

    const float b      = 1.5f * r;
    const float r15sq  = b * b;
    const float rr     = r * r;
    const float E2     = 7.3890562f;
    const float c2a    = 4.0f / (E2 * rr);
    const float c2b    = 12.0f / (E2 * r);
    const float c2c    = 9.0f / E2;
    const float n2orr  = -2.0f / rr;

    const float px0 = 0.5f * (float)(tx * 8 + lx);
    const float px1 = px0 + 2.0f;
    const float py  = 0.5f * (float)(ty * 8 + ly);
    const float pz  = 0.5f * (float)(tz * 8 + lz);

    __shared__ float4 sa[256];

    const int lt = type * NTILES + t;
    const int n  = min(cnt[lt], CAP);
    const int len   = (n + nseg - 1) / nseg;
    const int start = s * len;
    const int end   = min(n, start + len);
    const unsigned short* __restrict__ lst = lists + (size_t)lt * CAP;

    float acc0 = 0.0f, acc1 = 0.0f;

    for (int base = start; base < end; base += 256) {
        const int m = min(256, end - base);
        if (tid < m) {
            const int idx = (int)lst[base + tid];
            sa[tid] = make_float4(vecs[3 * idx + 0] + 23.5f,
                                  vecs[3 * idx + 1] + 23.5f,
                                  vecs[3 * idx + 2] + 23.5f, 0.0f);
        }
        __syncthreads();

        for (int j = 0; j < m; ++j) {
            const float4 a = sa[j];               // one b128 LDS broadcast
            const float dy  = a.y - py;
            const float dz  = a.z - pz;
            const float syz = fmaf(dy, dy, dz * dz);
            const float dx0 = a.x - px0;
            const float d2a = fmaf(dx0, dx0, syz);
            const float dx1 = a.x - px1;
            const float d2b = fmaf(dx1, dx1, syz);
            const bool h0 = d2a < r15sq;
            const bool h1 = d2b < r15sq;
            if (__ballot(h0 | h1) == 0ull) continue;   // whole-wave miss cull
            if (h0) {
                const float d = sqrtf(d2a);
                acc0 += (d < r) ? __expf(n2orr * d2a)
                                : fmaf(c2a, d2a, fmaf(-c2b, d, c2c));
            }
            if (h1) {
                const float d = sqrtf(d2b);
                acc1 += (d < r) ? __expf(n2orr * d2b)
                                : fmaf(c2a, d2b, fmaf(-c2b, d, c2c));
            }
        }
        __syncthreads();
    }

    const int X0 = tx * 8 + lx;
    const int Y  = ty * 8 + ly;
    const int Z  = tz * 8 + lz;
    float* __restrict__ o = copies + (size_t)s * GRID_FLOATS
                                   + (size_t)type * NG * NG * NG;
    o[((X0      * NG) + Y) * NG + Z] = acc0;
    o[(((X0 + 4) * NG) + Y) * NG + Z] = acc1;
}

// Phase 3: out[i] = sum over segments of copies[s][i]. float4, plain stores.
__global__ __launch_bounds__(256) void reduce_kernel(
    const float* __restrict__ copies,
    float* __restrict__ out,
    int nseg)
{
    const int i4 = blockIdx.x * 256 + threadIdx.x;   // float4 index
    if (i4 >= GRID_FLOATS / 4) return;
    const float4* __restrict__ c = (const float4*)copies;
    float4 acc = c[i4];
    for (int s = 1; s < nseg; ++s) {
        const float4 v = c[(size_t)s * (GRID_FLOATS / 4) + i4];
        acc.x += v.x; acc.y += v.y; acc.z += v.z; acc.w += v.w;
    }
    ((float4*)out)[i4] = acc;
}

extern "C" void kernel_launch(void* const* d_in, const int* in_sizes, int n_in,
                              void* d_out, int out_size, void* d_ws, size_t ws_size,
                              hipStream_t stream) {
    const float* vC = (const float*)d_in[0];
    const float* vN = (const float*)d_in[1];
    const float* vO = (const float*)d_in[2];
    float* out = (float*)d_out;

    int* cnt = (int*)d_ws;
    unsigned short* lists = (unsigned short*)((char*)d_ws + LISTS_OFF);
    float* copies = (float*)((char*)d_ws + COPIES_OFF);

    // clamp segment count to what the workspace can hold
    const size_t copy_bytes = (size_t)GRID_FLOATS * sizeof(float);
    long avail = (long)((ws_size - COPIES_OFF) / copy_bytes);
    int nseg = (int)(avail < 1 ? 1 : (avail > MAXSEG ? MAXSEG : avail));

    const int natoms = in_sizes[0] / 3;   // 16384

    hipMemsetAsync(cnt, 0, 3 * NTILES * sizeof(int), stream);

    dim3 bgrid((natoms + 255) / 256, 3, 1);
    bin_kernel<<<bgrid, 256, 0, stream>>>(vC, vN, vO, cnt, lists, natoms);

    dim3 ggrid(NTILES * nseg, 3, 1);
    gather_seg<<<ggrid, 256, 0, stream>>>(vC, vN, vO, cnt, lists, copies, nseg);

    dim3 rgrid((GRID_FLOATS / 4 + 255) / 256, 1, 1);
    reduce_kernel<<<rgrid, 256, 0, stream>>>(copies, out, nseg);
}